// Round 6
// baseline (56.059 us; speedup 1.0000x reference)
//
#include <hip/hip_runtime.h>

// Chamfer distance via MFMA, B=4, N=M=8192, fp32 3D points.
// d[n,m] = qsq[n] + tsq[m] - 2*q[n].t[m] via v_mfma_f32_32x32x16_bf16 with
// split-precision bf16 operands (13 of 16 k-slots):
//   s0..s8 : per coord c: qh_c*(-2th_c), qh_c*(-2tl_c), ql_c*(-2th_c)
//   s9,s10 : qsq_h*1, qsq_l*1   s11,s12: 1*tsq_h, 1*tsq_l   s13..15: 0
// Round-6 change: REGISTER BLOCKING. Each wave holds QT=4 query-tile A-frags;
// one B-frag load feeds 4 MFMA + 64 independent fmin (~140 cyc of work per
// load vs ~40 in round 5), with 1-deep explicit B prefetch. Loads, loop
// overhead, epilogue amortized 4x. No LDS staging (B-segment is L1-resident).

typedef short bf16x8 __attribute__((ext_vector_type(8)));
typedef float f32x16 __attribute__((ext_vector_type(16)));

constexpr int Bc  = 4;
constexpr int Nc  = 8192;
constexpr int NT  = Nc / 32;    // 256 query tiles of 32 points
constexpr int SEG = 8;          // target segments
constexpr int TPS = NT / SEG;   // 32 target tiles per segment
constexpr int QT  = 4;          // query tiles per wave (register blocking)

__device__ inline unsigned short f2bf(float x) {
    unsigned u = __float_as_uint(x);
    unsigned r = (u + 0x7FFFu + ((u >> 16) & 1u)) >> 16;   // RNE
    return (unsigned short)r;
}
__device__ inline float bf2f(unsigned short h) {
    return __uint_as_float(((unsigned)h) << 16);
}
__device__ inline unsigned pack2(unsigned short lo, unsigned short hi) {
    return (unsigned)lo | ((unsigned)hi << 16);
}

__global__ void init_out_inf(float* __restrict__ out, int n) {
    int i = blockIdx.x * blockDim.x + threadIdx.x;
    int stride = gridDim.x * blockDim.x;
    for (; i < n; i += stride) out[i] = __uint_as_float(0x7F800000u);
}

// One launch packs BOTH clouds into q-form and t-form fragment arrays.
// qf/tf: [2 clouds][Bc*NT*64] uint4. blockIdx.y = cloud.
__global__ void pack_both(const float* __restrict__ xyz1,
                          const float* __restrict__ xyz2,
                          uint4* __restrict__ qf, uint4* __restrict__ tf) {
    const int tid   = blockIdx.x * 256 + threadIdx.x;   // [0, Bc*NT*64)
    const int cloud = blockIdx.y;
    const float* src = cloud ? xyz2 : xyz1;
    const int lane = tid & 63;
    const int tile = (tid >> 6) & (NT - 1);
    const int b    = tid >> 14;
    const int pt   = tile * 32 + (lane & 31);
    const int kg   = lane >> 5;
    const float* p = src + ((size_t)b * Nc + pt) * 3;
    float x = p[0], y = p[1], z = p[2];
    float sq = x * x + y * y + z * z;
    unsigned short xh = f2bf(x), yh = f2bf(y), zh = f2bf(z);
    unsigned short xl = f2bf(x - bf2f(xh)), yl = f2bf(y - bf2f(yh)), zl = f2bf(z - bf2f(zh));
    unsigned short sh = f2bf(sq), sl = f2bf(sq - bf2f(sh));
    unsigned short m2xh = f2bf(-2.0f * bf2f(xh));
    unsigned short m2yh = f2bf(-2.0f * bf2f(yh));
    unsigned short m2zh = f2bf(-2.0f * bf2f(zh));
    unsigned short m2xl = f2bf(-2.0f * (x - bf2f(xh)));
    unsigned short m2yl = f2bf(-2.0f * (y - bf2f(yh)));
    unsigned short m2zl = f2bf(-2.0f * (z - bf2f(zh)));
    const unsigned short ONE = 0x3F80;
    uint4 q, t;
    if (kg == 0) {
        q.x = pack2(xh, xh); q.y = pack2(xl, yh);
        q.z = pack2(yh, yl); q.w = pack2(zh, zh);
        t.x = pack2(m2xh, m2xl); t.y = pack2(m2xh, m2yh);
        t.z = pack2(m2yl, m2yh); t.w = pack2(m2zh, m2zl);
    } else {
        q.x = pack2(zl, sh); q.y = pack2(sl, ONE);
        q.z = pack2(ONE, 0); q.w = 0;
        t.x = pack2(m2zh, ONE); t.y = pack2(ONE, sh);
        t.z = pack2(sl, 0);     t.w = 0;
    }
    const size_t FR = (size_t)Bc * NT * 64;
    qf[(size_t)cloud * FR + tid] = q;
    tf[(size_t)cloud * FR + tid] = t;
}

// Main: grid (NT/(4*QT), SEG, 2*Bc), 256 threads = 4 waves.
// blockIdx.z: dir = z>>2 (0: xyz1->xyz2, 1: xyz2->xyz1), b = z&3.
// Wave w holds QT=4 query tiles (blockIdx.x*16 + w*4 + qt), sweeps TPS
// target tiles of segment `seg`; pure running row-min, butterfly epilogue.
__global__ __launch_bounds__(256) void chamfer_rb(
    const uint4* __restrict__ qf,   // [2][Bc*NT*64]
    const uint4* __restrict__ tf,   // [2][Bc*NT*64]
    float* __restrict__ out) {
    const int tid = threadIdx.x, lane = tid & 63, wave = tid >> 6;
    const int z = blockIdx.z, dir = z >> 2, b = z & 3, seg = blockIdx.y;
    const int qc = dir, tc = dir ^ 1;
    const size_t FR = (size_t)Bc * NT * 64;

    const int tile0 = blockIdx.x * (4 * QT) + wave * QT;
    bf16x8 av[QT];
    #pragma unroll
    for (int qt = 0; qt < QT; ++qt)
        av[qt] = __builtin_bit_cast(bf16x8,
            qf[(size_t)qc * FR + ((size_t)(b * NT + tile0 + qt)) * 64 + lane]);

    f32x16 zc{};
    float rmin[QT][16];
    #pragma unroll
    for (int qt = 0; qt < QT; ++qt)
        #pragma unroll
        for (int r = 0; r < 16; ++r) rmin[qt][r] = INFINITY;

    const uint4* bp = tf + (size_t)tc * FR + ((size_t)(b * NT + seg * TPS)) * 64 + lane;
    bf16x8 bv = __builtin_bit_cast(bf16x8, bp[0]);
    #pragma unroll 2
    for (int mt = 0; mt < TPS; ++mt) {
        // 1-deep prefetch: issue next B-frag load before consuming current.
        bf16x8 nbv = bv;
        if (mt + 1 < TPS)
            nbv = __builtin_bit_cast(bf16x8, bp[(size_t)(mt + 1) * 64]);
        #pragma unroll
        for (int qt = 0; qt < QT; ++qt) {
            const f32x16 d = __builtin_amdgcn_mfma_f32_32x32x16_bf16(av[qt], bv, zc, 0, 0, 0);
            #pragma unroll
            for (int r = 0; r < 16; ++r) rmin[qt][r] = fminf(rmin[qt][r], d[r]);
        }
        bv = nbv;
    }

    // Epilogue per query tile: butterfly over the 32 columns (lane bits 0..4),
    // then lane 0 / lane 32 write 16 rows each via one global atomicMin.
    const int hi = lane >> 5;
    #pragma unroll
    for (int qt = 0; qt < QT; ++qt) {
        #pragma unroll
        for (int m = 1; m <= 16; m <<= 1)
            #pragma unroll
            for (int r = 0; r < 16; ++r)
                rmin[qt][r] = fminf(rmin[qt][r], __shfl_xor(rmin[qt][r], m));
        if ((lane & 31) == 0) {
            unsigned* d1 = (unsigned*)out + (size_t)dir * Bc * Nc + (size_t)b * Nc
                         + (size_t)(tile0 + qt) * 32;
            #pragma unroll
            for (int r = 0; r < 16; ++r) {
                const int row = (r & 3) + 8 * (r >> 2) + 4 * hi;   // C/D layout (m74/m101)
                atomicMin(&d1[row], __float_as_uint(fmaxf(rmin[qt][r], 0.0f)));
            }
        }
    }
}

// ---- Fallback (ws too small): round-2 expansion kernel ----
constexpr int QPT = 2, TPB = 256;
__global__ void pack_pts(const float* __restrict__ src, float4* __restrict__ dst, int npts) {
    int i = blockIdx.x * blockDim.x + threadIdx.x;
    if (i < npts) {
        float x = src[3 * i], y = src[3 * i + 1], z = src[3 * i + 2];
        dst[i] = make_float4(x, y, z, x * x + y * y + z * z);
    }
}
__global__ __launch_bounds__(TPB, 8) void chamfer_fb(
    const float* __restrict__ xyz1, const float* __restrict__ xyz2,
    const float4* __restrict__ p1, const float4* __restrict__ p2,
    float* __restrict__ out) {
    const int z = blockIdx.z, dir = z >> 2, b = z & 3, seg = blockIdx.y;
    const float*  qry  = dir ? xyz2 : xyz1;
    const float4* tgt4 = dir ? p1 : p2;
    float* o = out + (size_t)dir * Bc * Nc + (size_t)b * Nc;
    const int q0 = blockIdx.x * (TPB * QPT) + threadIdx.x;
    float m2x[QPT], m2y[QPT], m2z[QPT], qsq[QPT];
    #pragma unroll
    for (int j = 0; j < QPT; ++j) {
        const float* qp = qry + ((size_t)b * Nc + q0 + j * TPB) * 3;
        float x = qp[0], y = qp[1], zz = qp[2];
        m2x[j] = -2.f * x; m2y[j] = -2.f * y; m2z[j] = -2.f * zz;
        qsq[j] = x * x + y * y + zz * zz;
    }
    constexpr int seg_pts = Nc / 16;
    const float4* t = tgt4 + (size_t)b * Nc + (size_t)seg * seg_pts;
    float mn0[QPT], mn1[QPT];
    #pragma unroll
    for (int j = 0; j < QPT; ++j) { mn0[j] = INFINITY; mn1[j] = INFINITY; }
    #pragma unroll 4
    for (int i = 0; i < seg_pts; i += 2) {
        const float4 t0 = t[i], t1 = t[i + 1];
        #pragma unroll
        for (int j = 0; j < QPT; ++j) {
            mn0[j] = fminf(mn0[j], fmaf(m2x[j], t0.x, fmaf(m2y[j], t0.y, fmaf(m2z[j], t0.z, t0.w))));
            mn1[j] = fminf(mn1[j], fmaf(m2x[j], t1.x, fmaf(m2y[j], t1.y, fmaf(m2z[j], t1.z, t1.w))));
        }
    }
    #pragma unroll
    for (int j = 0; j < QPT; ++j) {
        float d = fmaxf(qsq[j] + fminf(mn0[j], mn1[j]), 0.f);
        atomicMin((unsigned*)(o + q0 + j * TPB), __float_as_uint(d));
    }
}

extern "C" void kernel_launch(void* const* d_in, const int* in_sizes, int n_in,
                              void* d_out, int out_size, void* d_ws, size_t ws_size,
                              hipStream_t stream) {
    const float* xyz1 = (const float*)d_in[0];
    const float* xyz2 = (const float*)d_in[1];
    float* out = (float*)d_out;

    const size_t FR = (size_t)Bc * NT * 64;               // 65536 uint4 per array
    const size_t need = 4 * FR * sizeof(uint4);           // 4 MiB (qf[2] + tf[2])

    init_out_inf<<<dim3(64), dim3(256), 0, stream>>>(out, out_size);

    if (ws_size >= need) {
        uint4* qf = (uint4*)d_ws;          // [2][FR]
        uint4* tf = qf + 2 * FR;           // [2][FR]
        pack_both<<<dim3(FR / 256, 2), dim3(256), 0, stream>>>(xyz1, xyz2, qf, tf);
        dim3 grid(NT / (4 * QT), SEG, 2 * Bc);            // 16 x 8 x 8 = 1024 blocks
        chamfer_rb<<<grid, dim3(256), 0, stream>>>(qf, tf, out);
    } else if (ws_size >= 2 * (size_t)Bc * Nc * sizeof(float4)) {
        float4* p1 = (float4*)d_ws;
        float4* p2 = p1 + Bc * Nc;
        pack_pts<<<dim3(Bc * Nc / 256), dim3(256), 0, stream>>>(xyz1, p1, Bc * Nc);
        pack_pts<<<dim3(Bc * Nc / 256), dim3(256), 0, stream>>>(xyz2, p2, Bc * Nc);
        dim3 grid(Nc / (TPB * QPT), 16, 2 * Bc);
        chamfer_fb<<<grid, dim3(TPB), 0, stream>>>(xyz1, xyz2, p1, p2, out);
    }
}

// Round 7
// 53.580 us; speedup vs baseline: 1.0463x; 1.0463x over previous
//
#include <hip/hip_runtime.h>

// Chamfer distance via MFMA, B=4, N=M=8192, fp32 3D points.
// d[n,m] = qsq[n] + tsq[m] - 2*q[n].t[m] via v_mfma_f32_32x32x16_bf16 with
// split-precision bf16 operands (13 of 16 k-slots):
//   s0..s8 : per coord c: qh_c*(-2th_c), qh_c*(-2tl_c), ql_c*(-2th_c)
//   s9,s10 : qsq_h*1, qsq_l*1   s11,s12: 1*tsq_h, 1*tsq_l   s13..15: 0
// Round-7: LDS-shared B-segment. 512-thread blocks (8 waves = 8 query tiles)
// stage the 32KB B-segment into LDS ONCE (L2 traffic 537->67 MB), sweep via
// conflict-free ds_read_b128. 2 B-tiles/iter so fmin pairs fuse to v_min3.
// Pure running row-min per pass; two passes (one per direction) in one launch.

typedef short bf16x8 __attribute__((ext_vector_type(8)));
typedef float f32x16 __attribute__((ext_vector_type(16)));

constexpr int Bc  = 4;
constexpr int Nc  = 8192;
constexpr int NT  = Nc / 32;    // 256 tiles of 32 points
constexpr int SEG = 8;          // target segments
constexpr int TPS = NT / SEG;   // 32 target tiles per segment
constexpr int WPB = 8;          // waves (query tiles) per block

__device__ inline unsigned short f2bf(float x) {
    unsigned u = __float_as_uint(x);
    unsigned r = (u + 0x7FFFu + ((u >> 16) & 1u)) >> 16;   // RNE
    return (unsigned short)r;
}
__device__ inline float bf2f(unsigned short h) {
    return __uint_as_float(((unsigned)h) << 16);
}
__device__ inline unsigned pack2(unsigned short lo, unsigned short hi) {
    return (unsigned)lo | ((unsigned)hi << 16);
}

__global__ void init_out_inf(float* __restrict__ out, int n) {
    int i = blockIdx.x * blockDim.x + threadIdx.x;
    int stride = gridDim.x * blockDim.x;
    for (; i < n; i += stride) out[i] = __uint_as_float(0x7F800000u);
}

// One launch packs BOTH clouds into q-form and t-form fragment arrays.
// qf/tf: [2 clouds][Bc*NT*64] uint4. blockIdx.y = cloud.
__global__ void pack_both(const float* __restrict__ xyz1,
                          const float* __restrict__ xyz2,
                          uint4* __restrict__ qf, uint4* __restrict__ tf) {
    const int tid   = blockIdx.x * 256 + threadIdx.x;   // [0, Bc*NT*64)
    const int cloud = blockIdx.y;
    const float* src = cloud ? xyz2 : xyz1;
    const int lane = tid & 63;
    const int tile = (tid >> 6) & (NT - 1);
    const int b    = tid >> 14;
    const int pt   = tile * 32 + (lane & 31);
    const int kg   = lane >> 5;
    const float* p = src + ((size_t)b * Nc + pt) * 3;
    float x = p[0], y = p[1], z = p[2];
    float sq = x * x + y * y + z * z;
    unsigned short xh = f2bf(x), yh = f2bf(y), zh = f2bf(z);
    unsigned short xl = f2bf(x - bf2f(xh)), yl = f2bf(y - bf2f(yh)), zl = f2bf(z - bf2f(zh));
    unsigned short sh = f2bf(sq), sl = f2bf(sq - bf2f(sh));
    unsigned short m2xh = f2bf(-2.0f * bf2f(xh));
    unsigned short m2yh = f2bf(-2.0f * bf2f(yh));
    unsigned short m2zh = f2bf(-2.0f * bf2f(zh));
    unsigned short m2xl = f2bf(-2.0f * (x - bf2f(xh)));
    unsigned short m2yl = f2bf(-2.0f * (y - bf2f(yh)));
    unsigned short m2zl = f2bf(-2.0f * (z - bf2f(zh)));
    const unsigned short ONE = 0x3F80;
    uint4 q, t;
    if (kg == 0) {
        q.x = pack2(xh, xh); q.y = pack2(xl, yh);
        q.z = pack2(yh, yl); q.w = pack2(zh, zh);
        t.x = pack2(m2xh, m2xl); t.y = pack2(m2xh, m2yh);
        t.z = pack2(m2yl, m2yh); t.w = pack2(m2zh, m2zl);
    } else {
        q.x = pack2(zl, sh); q.y = pack2(sl, ONE);
        q.z = pack2(ONE, 0); q.w = 0;
        t.x = pack2(m2zh, ONE); t.y = pack2(ONE, sh);
        t.z = pack2(sl, 0);     t.w = 0;
    }
    const size_t FR = (size_t)Bc * NT * 64;
    qf[(size_t)cloud * FR + tid] = q;
    tf[(size_t)cloud * FR + tid] = t;
}

// Main: grid (NT/WPB, SEG, 2*Bc), 512 threads = 8 waves.
// blockIdx.z: dir = z>>2 (0: xyz1->xyz2, 1: xyz2->xyz1), b = z&3.
// Block stages its B-segment (TPS*64 uint4 = 32KB) in LDS; wave w sweeps it
// against query tile blockIdx.x*WPB + w with a pure running row-min.
__global__ __launch_bounds__(512, 6) void chamfer_lds(
    const uint4* __restrict__ qf,   // [2][Bc*NT*64]
    const uint4* __restrict__ tf,   // [2][Bc*NT*64]
    float* __restrict__ out) {
    __shared__ uint4 sB[TPS * 64];                 // 32 KB
    const int tid = threadIdx.x, lane = tid & 63, wave = tid >> 6;
    const int z = blockIdx.z, dir = z >> 2, b = z & 3, seg = blockIdx.y;
    const int qc = dir, tc = dir ^ 1;
    const size_t FR = (size_t)Bc * NT * 64;

    // Stage B-segment: 2048 uint4, 512 threads -> 4 coalesced 16B stores each.
    const uint4* bseg = tf + (size_t)tc * FR + ((size_t)(b * NT + seg * TPS)) * 64;
    #pragma unroll
    for (int i = 0; i < TPS * 64 / 512; ++i)
        sB[tid + i * 512] = bseg[tid + i * 512];

    const int n_tile = blockIdx.x * WPB + wave;
    const bf16x8 av = __builtin_bit_cast(bf16x8,
        qf[(size_t)qc * FR + ((size_t)(b * NT + n_tile)) * 64 + lane]);
    f32x16 zc{};
    float rmin[16];
    #pragma unroll
    for (int r = 0; r < 16; ++r) rmin[r] = INFINITY;

    __syncthreads();

    // Sweep 32 B-tiles from LDS, 2 per iteration (fmin pair -> v_min3).
    #pragma unroll 2
    for (int mt = 0; mt < TPS; mt += 2) {
        const bf16x8 bv0 = __builtin_bit_cast(bf16x8, sB[mt * 64 + lane]);
        const bf16x8 bv1 = __builtin_bit_cast(bf16x8, sB[mt * 64 + 64 + lane]);
        const f32x16 d0 = __builtin_amdgcn_mfma_f32_32x32x16_bf16(av, bv0, zc, 0, 0, 0);
        const f32x16 d1 = __builtin_amdgcn_mfma_f32_32x32x16_bf16(av, bv1, zc, 0, 0, 0);
        #pragma unroll
        for (int r = 0; r < 16; ++r)
            rmin[r] = fminf(rmin[r], fminf(d0[r], d1[r]));   // v_min3_f32
    }

    // Epilogue: butterfly over the 32 columns (lane bits 0..4), then lanes
    // 0 and 32 write 16 rows each via one global atomicMin per row.
    #pragma unroll
    for (int m = 1; m <= 16; m <<= 1)
        #pragma unroll
        for (int r = 0; r < 16; ++r)
            rmin[r] = fminf(rmin[r], __shfl_xor(rmin[r], m));
    if ((lane & 31) == 0) {
        const int hi = lane >> 5;
        unsigned* d1p = (unsigned*)out + (size_t)dir * Bc * Nc + (size_t)b * Nc
                      + (size_t)n_tile * 32;
        #pragma unroll
        for (int r = 0; r < 16; ++r) {
            const int row = (r & 3) + 8 * (r >> 2) + 4 * hi;   // C/D layout (m74/m101)
            atomicMin(&d1p[row], __float_as_uint(fmaxf(rmin[r], 0.0f)));
        }
    }
}

// ---- Fallback (ws too small): round-2 expansion kernel ----
constexpr int QPT = 2, TPB = 256;
__global__ void pack_pts(const float* __restrict__ src, float4* __restrict__ dst, int npts) {
    int i = blockIdx.x * blockDim.x + threadIdx.x;
    if (i < npts) {
        float x = src[3 * i], y = src[3 * i + 1], z = src[3 * i + 2];
        dst[i] = make_float4(x, y, z, x * x + y * y + z * z);
    }
}
__global__ __launch_bounds__(TPB, 8) void chamfer_fb(
    const float* __restrict__ xyz1, const float* __restrict__ xyz2,
    const float4* __restrict__ p1, const float4* __restrict__ p2,
    float* __restrict__ out) {
    const int z = blockIdx.z, dir = z >> 2, b = z & 3, seg = blockIdx.y;
    const float*  qry  = dir ? xyz2 : xyz1;
    const float4* tgt4 = dir ? p1 : p2;
    float* o = out + (size_t)dir * Bc * Nc + (size_t)b * Nc;
    const int q0 = blockIdx.x * (TPB * QPT) + threadIdx.x;
    float m2x[QPT], m2y[QPT], m2z[QPT], qsq[QPT];
    #pragma unroll
    for (int j = 0; j < QPT; ++j) {
        const float* qp = qry + ((size_t)b * Nc + q0 + j * TPB) * 3;
        float x = qp[0], y = qp[1], zz = qp[2];
        m2x[j] = -2.f * x; m2y[j] = -2.f * y; m2z[j] = -2.f * zz;
        qsq[j] = x * x + y * y + zz * zz;
    }
    constexpr int seg_pts = Nc / 16;
    const float4* t = tgt4 + (size_t)b * Nc + (size_t)seg * seg_pts;
    float mn0[QPT], mn1[QPT];
    #pragma unroll
    for (int j = 0; j < QPT; ++j) { mn0[j] = INFINITY; mn1[j] = INFINITY; }
    #pragma unroll 4
    for (int i = 0; i < seg_pts; i += 2) {
        const float4 t0 = t[i], t1 = t[i + 1];
        #pragma unroll
        for (int j = 0; j < QPT; ++j) {
            mn0[j] = fminf(mn0[j], fmaf(m2x[j], t0.x, fmaf(m2y[j], t0.y, fmaf(m2z[j], t0.z, t0.w))));
            mn1[j] = fminf(mn1[j], fmaf(m2x[j], t1.x, fmaf(m2y[j], t1.y, fmaf(m2z[j], t1.z, t1.w))));
        }
    }
    #pragma unroll
    for (int j = 0; j < QPT; ++j) {
        float d = fmaxf(qsq[j] + fminf(mn0[j], mn1[j]), 0.f);
        atomicMin((unsigned*)(o + q0 + j * TPB), __float_as_uint(d));
    }
}

extern "C" void kernel_launch(void* const* d_in, const int* in_sizes, int n_in,
                              void* d_out, int out_size, void* d_ws, size_t ws_size,
                              hipStream_t stream) {
    const float* xyz1 = (const float*)d_in[0];
    const float* xyz2 = (const float*)d_in[1];
    float* out = (float*)d_out;

    const size_t FR = (size_t)Bc * NT * 64;               // 65536 uint4 per array
    const size_t need = 4 * FR * sizeof(uint4);           // 4 MiB (qf[2] + tf[2])

    init_out_inf<<<dim3(64), dim3(256), 0, stream>>>(out, out_size);

    if (ws_size >= need) {
        uint4* qf = (uint4*)d_ws;          // [2][FR]
        uint4* tf = qf + 2 * FR;           // [2][FR]
        pack_both<<<dim3(FR / 256, 2), dim3(256), 0, stream>>>(xyz1, xyz2, qf, tf);
        dim3 grid(NT / WPB, SEG, 2 * Bc);                 // 32 x 8 x 8 = 2048 blocks
        chamfer_lds<<<grid, dim3(512), 0, stream>>>(qf, tf, out);
    } else if (ws_size >= 2 * (size_t)Bc * Nc * sizeof(float4)) {
        float4* p1 = (float4*)d_ws;
        float4* p2 = p1 + Bc * Nc;
        pack_pts<<<dim3(Bc * Nc / 256), dim3(256), 0, stream>>>(xyz1, p1, Bc * Nc);
        pack_pts<<<dim3(Bc * Nc / 256), dim3(256), 0, stream>>>(xyz2, p2, Bc * Nc);
        dim3 grid(Nc / (TPB * QPT), 16, 2 * Bc);
        chamfer_fb<<<grid, dim3(TPB), 0, stream>>>(xyz1, xyz2, p1, p2, out);
    }
}